// Round 3
// baseline (447.795 us; speedup 1.0000x reference)
//
#include <hip/hip_runtime.h>
#include <hip/hip_bf16.h>
#include <cmath>

typedef __bf16 bf16_t;
typedef __bf16 bf16x8 __attribute__((ext_vector_type(8)));
typedef float f32x4 __attribute__((ext_vector_type(4)));
typedef float f32x16 __attribute__((ext_vector_type(16)));
typedef unsigned short u16;
typedef unsigned int u32;

// ---------------- async global->LDS (16B per lane) ----------------
__device__ __forceinline__ void load16(const bf16_t* g, bf16_t* l) {
  __builtin_amdgcn_global_load_lds((const __attribute__((address_space(1))) u32*)g,
                                   (__attribute__((address_space(3))) u32*)l, 16, 0, 0);
}

__device__ __forceinline__ u32 pk2(float a, float b) {
  bf16_t x = (bf16_t)a, y = (bf16_t)b;
  u16 ux = __builtin_bit_cast(u16, x), uy = __builtin_bit_cast(u16, y);
  return (u32)ux | ((u32)uy << 16);
}

union V4U { u32 w[4]; bf16x8 v; };

// ---------------- weight transpose + fp32->bf16 ----------------
__global__ __launch_bounds__(256) void transpose_w(const float* __restrict__ Wsrc,
                                                   bf16_t* __restrict__ Wt, int Kd, int Nd) {
  __shared__ float tile[32][33];
  int n0 = blockIdx.x * 32, k0 = blockIdx.y * 32;
  int tx = threadIdx.x & 31, ty = threadIdx.x >> 5;  // 32x8
  for (int i = ty; i < 32; i += 8)
    tile[i][tx] = Wsrc[(size_t)(k0 + i) * Nd + n0 + tx];
  __syncthreads();
  for (int i = ty; i < 32; i += 8)
    Wt[(size_t)(n0 + i) * Kd + k0 + tx] = (bf16_t)tile[tx][i];
}

// ---------------- RoPE table: cos/sin [2048][32] ----------------
__global__ void rope_tab(float* __restrict__ c, float* __restrict__ s) {
  int pos = blockIdx.x, t = threadIdx.x;  // 32 threads
  float e = (float)(2 * t) / 64.0f;
  float inv = powf(10000.0f, -e);
  float a = (float)pos * inv;
  c[pos * 32 + t] = cosf(a);
  s[pos * 32 + t] = sinf(a);
}

// ---------------- LayerNorm: one row per block, width W ----------------
template <typename TI, int W>
__global__ __launch_bounds__(256) void ln_kernel(const TI* __restrict__ in,
                                                 const float* __restrict__ g,
                                                 const float* __restrict__ b,
                                                 bf16_t* __restrict__ out) {
  constexpr int PT = W / 256;
  int row = blockIdx.x;
  const TI* p = in + (size_t)row * W;
  float vals[PT];
  float s = 0.f, q = 0.f;
  for (int i = 0; i < PT; ++i) {
    float v = (float)p[threadIdx.x + i * 256];
    vals[i] = v; s += v; q += v * v;
  }
  for (int off = 32; off; off >>= 1) { s += __shfl_xor(s, off); q += __shfl_xor(q, off); }
  __shared__ float red[8];
  int wave = threadIdx.x >> 6, lane = threadIdx.x & 63;
  if (lane == 0) { red[wave] = s; red[4 + wave] = q; }
  __syncthreads();
  s = red[0] + red[1] + red[2] + red[3];
  q = red[4] + red[5] + red[6] + red[7];
  float mu = s * (1.0f / W);
  float var = q * (1.0f / W) - mu * mu;
  float rstd = rsqrtf(var + 1e-5f);
  bf16_t* op = out + (size_t)row * W;
  for (int i = 0; i < PT; ++i) {
    int cix = threadIdx.x + i * 256;
    op[cix] = (bf16_t)((vals[i] - mu) * rstd * g[cix] + b[cix]);
  }
}

// ---------------- GEMM (m97 structure): C[m][n] = sum_k A[m][k]*Bt[n][k] ----------------
enum { EPI_QKV = 0, EPI_RESID = 1, EPI_GELU = 2 };

template <int EPI>
__global__ __launch_bounds__(256, 2) void gemm_bt(
    const bf16_t* __restrict__ A, const bf16_t* __restrict__ Bt, int M, int Nn, int K,
    const float* __restrict__ bias, const float* __restrict__ resid,
    float* __restrict__ outf, bf16_t* __restrict__ outb,
    bf16_t* __restrict__ qb, bf16_t* __restrict__ kb, bf16_t* __restrict__ vtb,
    const float* __restrict__ ropeC, const float* __restrict__ ropeS) {
  __shared__ bf16_t lsA[128 * 32];
  __shared__ bf16_t lsB[128 * 32];
  const int tid = threadIdx.x;
  const int lane = tid & 63;
  const int wave = tid >> 6;
  const int l16 = lane & 15, quad = lane >> 4;
  const int wm = (wave >> 1) * 64, wn = (wave & 1) * 64;
  const int m0 = blockIdx.y * 128, n0 = blockIdx.x * 128;

  f32x4 acc[4][4];
  for (int i = 0; i < 4; ++i)
    for (int j = 0; j < 4; ++j) acc[i][j] = {0.f, 0.f, 0.f, 0.f};

  for (int kk = 0; kk < K; kk += 32) {
    __syncthreads();
    for (int i = 0; i < 2; ++i) {
      int s = tid + i * 256;
      int row = s >> 2, ch = s & 3;
      load16(A + (size_t)(m0 + row) * K + kk + ch * 8, lsA + s * 8);
      load16(Bt + (size_t)(n0 + row) * K + kk + ch * 8, lsB + s * 8);
    }
    __syncthreads();
    bf16x8 af[4], bfr[4];
    for (int t = 0; t < 4; ++t) {
      af[t] = *(const bf16x8*)(lsA + (wm + t * 16 + l16) * 32 + quad * 8);
      bfr[t] = *(const bf16x8*)(lsB + (wn + t * 16 + l16) * 32 + quad * 8);
    }
    for (int mt = 0; mt < 4; ++mt)
      for (int nt = 0; nt < 4; ++nt)
        acc[mt][nt] = __builtin_amdgcn_mfma_f32_16x16x32_bf16(af[mt], bfr[nt], acc[mt][nt], 0, 0, 0);
  }

  // epilogue: row = m0+wm+mt*16+quad*4+r, col = n0+wn+nt*16+l16
  for (int mt = 0; mt < 4; ++mt) {
    for (int nt = 0; nt < 4; ++nt) {
      int gn = n0 + wn + nt * 16 + l16;
      int gm0 = m0 + wm + mt * 16 + quad * 4;
      if constexpr (EPI == EPI_QKV) {
        int which = gn >> 10;              // 0=q 1=k 2=v (uniform per nt)
        int hd = gn & 1023, head = hd >> 6, d = hd & 63;
        if (which == 2) {
          u32 lo, hi;
          {
            float v0 = acc[mt][nt][0] + bias[gn];
            float v1 = acc[mt][nt][1] + bias[gn];
            float v2 = acc[mt][nt][2] + bias[gn];
            float v3 = acc[mt][nt][3] + bias[gn];
            lo = pk2(v0, v1);
            hi = pk2(v2, v3);
          }
          int b = gm0 >> 11, pos = gm0 & 2047;
          int bh = b * 16 + head;
          uint2 pk; pk.x = lo; pk.y = hi;
          *(uint2*)(vtb + ((size_t)bh * 64 + d) * 2048 + pos) = pk;
        } else {
          bf16_t* dst = (which == 0) ? qb : kb;
          int t = d >> 1;
          for (int r = 0; r < 4; ++r) {
            float v = acc[mt][nt][r] + bias[gn];
            float pn = __shfl_xor(v, 1);  // partner column (d^1), same row
            int gm = gm0 + r;
            int b = gm >> 11, pos = gm & 2047;
            float cc = ropeC[pos * 32 + t], ss = ropeS[pos * 32 + t];
            float o = (d & 1) ? (v * cc + pn * ss) : (v * cc - pn * ss);
            dst[(((size_t)(b * 16 + head)) * 2048 + pos) * 64 + d] = (bf16_t)o;
          }
        }
      } else if constexpr (EPI == EPI_GELU) {
        for (int r = 0; r < 4; ++r) {
          int gm = gm0 + r;
          float v = acc[mt][nt][r] + bias[gn];
          float g = 0.5f * v * (1.0f + erff(v * 0.70710678118654752f));
          outb[(size_t)gm * Nn + gn] = (bf16_t)g;
        }
      } else {  // EPI_RESID: out = acc + bias + resid (fp32)
        for (int r = 0; r < 4; ++r) {
          int gm = gm0 + r;
          size_t idx = (size_t)gm * Nn + gn;
          outf[idx] = acc[mt][nt][r] + bias[gn] + resid[idx];
        }
      }
    }
  }
}

// ---------------- Flash attention, 32x32 MFMA, S^T/O^T orientation ----------------
// q,k: [BH][2048][64] bf16 (RoPE applied). vt: [BH][64][2048] bf16.
// o: [B][N][H*64] bf16. grid: (16 q-tiles, 32 bh), 256 threads, 32 q-rows/wave.
// Double-buffered K/V staging, one barrier per K-tile.
// 32x32x16 layouts: A[m=lane&31][k=(lane>>5)*8+j]; B[k=(lane>>5)*8+j][n=lane&31];
// C/D: col=lane&31, row=(reg&3)+8*(reg>>2)+4*(lane>>5).
__global__ __launch_bounds__(256, 2) void attn_kernel(
    const bf16_t* __restrict__ q, const bf16_t* __restrict__ k,
    const bf16_t* __restrict__ vt, bf16_t* __restrict__ o) {
  __shared__ bf16_t lsK[2][128 * 64];   // [key][d], 16B chunks swizzled: slot=c^(row&7)
  __shared__ bf16_t lsV[2][64 * 128];   // [d][key], slot=c^(row&7), 16 chunks/row

  const int tid = threadIdx.x, lane = tid & 63, wave = tid >> 6;
  const int c31 = lane & 31, hi = lane >> 5, h7 = c31 & 7;
  const int bh = blockIdx.y, qt = blockIdx.x;
  const int b = bh >> 4, h = bh & 15;
  const bf16_t* qp = q + (size_t)bh * 2048 * 64;
  const bf16_t* kp = k + (size_t)bh * 2048 * 64;
  const bf16_t* vp = vt + (size_t)bh * 64 * 2048;
  const int qrow0 = qt * 128 + wave * 32;
  const int qrow = qrow0 + c31;

  // Q B-frags: B[k=d][n=qrow]: lane needs q[qrow][ks*16+hi*8 .. +7], scaled by
  // 0.125*log2(e) so S is in log2 domain (exp2 instead of exp).
  const float QS = 0.18033688011112042f;
  bf16x8 qb[4];
#pragma unroll
  for (int ks = 0; ks < 4; ++ks) {
    bf16x8 t = *(const bf16x8*)(qp + (size_t)qrow * 64 + ks * 16 + hi * 8);
#pragma unroll
    for (int j = 0; j < 8; ++j) t[j] = (bf16_t)((float)t[j] * QS);
    qb[ks] = t;
  }

  f32x16 oacc[2];
  oacc[0] = 0.f; oacc[1] = 0.f;
  float mstate = -3.0e38f, lstate = 0.f;

  // staging: per thread 4 K-chunks + 4 V-chunks of 16B
  auto stage = [&](int kt, int buf) {
    const bf16_t* kg = kp + (size_t)kt * 128 * 64;
    bf16_t* lk = &lsK[buf][0];
    bf16_t* lv = &lsV[buf][0];
#pragma unroll
    for (int i = 0; i < 4; ++i) {
      int s = tid + i * 256;
      int kr = s >> 3, kc = (s & 7) ^ (kr & 7);
      load16(kg + (size_t)kr * 64 + kc * 8, lk + s * 8);
      int vr = s >> 4, vc = (s & 15) ^ (vr & 7);
      load16(vp + (size_t)vr * 2048 + kt * 128 + vc * 8, lv + s * 8);
    }
  };

  stage(0, 0);
  for (int kt = 0; kt < 16; ++kt) {
    __syncthreads();                    // drains async loads -> buf[kt&1] ready
    if (kt < 15) stage(kt + 1, (kt + 1) & 1);
    const bf16_t* lk = &lsK[kt & 1][0];
    const bf16_t* lv = &lsV[kt & 1][0];

    // S^T = K * Q^T : sacc[nt] covers keys nt*32..+31 x qrows (col=c31)
    f32x16 sacc[4];
    sacc[0] = 0.f; sacc[1] = 0.f; sacc[2] = 0.f; sacc[3] = 0.f;
#pragma unroll
    for (int ks = 0; ks < 4; ++ks) {
      int cs = ((ks * 2 + hi) ^ h7) * 8;
#pragma unroll
      for (int nt = 0; nt < 4; ++nt) {
        bf16x8 kf = *(const bf16x8*)(lk + (nt * 32 + c31) * 64 + cs);
        sacc[nt] = __builtin_amdgcn_mfma_f32_32x32x16_bf16(kf, qb[ks], sacc[nt], 0, 0, 0);
      }
    }

    // online softmax (log2 domain); all state per-lane for qrow=c31
    float mx = sacc[0][0];
#pragma unroll
    for (int nt = 0; nt < 4; ++nt)
#pragma unroll
      for (int r = 0; r < 16; ++r) mx = fmaxf(mx, sacc[nt][r]);
    mx = fmaxf(mx, __shfl_xor(mx, 32));
    float mnew = fmaxf(mstate, mx);
    float alpha = exp2f(mstate - mnew);
    mstate = mnew;
    float rs = 0.f;
    u32 u[4][4][2];
#pragma unroll
    for (int nt = 0; nt < 4; ++nt)
#pragma unroll
      for (int t = 0; t < 4; ++t) {
        float p0 = exp2f(sacc[nt][4 * t + 0] - mnew);
        float p1 = exp2f(sacc[nt][4 * t + 1] - mnew);
        float p2 = exp2f(sacc[nt][4 * t + 2] - mnew);
        float p3 = exp2f(sacc[nt][4 * t + 3] - mnew);
        rs += (p0 + p1) + (p2 + p3);
        u[nt][t][0] = pk2(p0, p1);
        u[nt][t][1] = pk2(p2, p3);
      }
    rs += __shfl_xor(rs, 32);
    lstate = lstate * alpha + rs;
#pragma unroll
    for (int dt = 0; dt < 2; ++dt)
#pragma unroll
      for (int r = 0; r < 16; ++r) oacc[dt][r] *= alpha;

    // O^T += V^T * P^T. B-frag(P^T) for ks: keys ks*16+hi*8..+7 at qrow=c31.
    // frag = [half0's u[n][2(ks&1)+hi], half1's same] -> cross-half exchange.
#pragma unroll
    for (int ks = 0; ks < 8; ++ks) {
      int n = ks >> 1, t0 = (ks & 1) * 2;
      u32 a0 = u[n][t0][0], a1 = u[n][t0][1];
      u32 b0 = u[n][t0 + 1][0], b1 = u[n][t0 + 1][1];
      u32 ax0 = (u32)__shfl_xor((int)a0, 32), ax1 = (u32)__shfl_xor((int)a1, 32);
      u32 bx0 = (u32)__shfl_xor((int)b0, 32), bx1 = (u32)__shfl_xor((int)b1, 32);
      V4U f;
      f.w[0] = hi ? bx0 : a0;
      f.w[1] = hi ? bx1 : a1;
      f.w[2] = hi ? b0 : ax0;
      f.w[3] = hi ? b1 : ax1;
      bf16x8 pf = f.v;
      int cs = ((ks * 2 + hi) ^ h7) * 8;
#pragma unroll
      for (int dt = 0; dt < 2; ++dt) {
        bf16x8 vf = *(const bf16x8*)(lv + (dt * 32 + c31) * 128 + cs);
        oacc[dt] = __builtin_amdgcn_mfma_f32_32x32x16_bf16(vf, pf, oacc[dt], 0, 0, 0);
      }
    }
  }

  // epilogue: O^T[d][qrow], lane col=qrow=c31, row d=(reg&3)+8*(reg>>2)+4*hi+32*dt
  float inv = 1.0f / lstate;
  bf16_t* orow = o + ((size_t)(b * 2048 + qrow)) * 1024 + h * 64;
#pragma unroll
  for (int dt = 0; dt < 2; ++dt)
#pragma unroll
    for (int t = 0; t < 4; ++t) {
      int d0 = dt * 32 + 8 * t + 4 * hi;
      uint2 pk;
      pk.x = pk2(oacc[dt][4 * t + 0] * inv, oacc[dt][4 * t + 1] * inv);
      pk.y = pk2(oacc[dt][4 * t + 2] * inv, oacc[dt][4 * t + 3] * inv);
      *(uint2*)(orow + d0) = pk;
    }
}

// ---------------- launch ----------------
extern "C" void kernel_launch(void* const* d_in, const int* in_sizes, int n_in,
                              void* d_out, int out_size, void* d_ws, size_t ws_size,
                              hipStream_t stream) {
  const float* x = (const float*)d_in[0];
  const float* ln1_g = (const float*)d_in[1];
  const float* ln1_b = (const float*)d_in[2];
  const float* qkv_w = (const float*)d_in[3];
  const float* qkv_b = (const float*)d_in[4];
  const float* proj_w = (const float*)d_in[5];
  const float* proj_b = (const float*)d_in[6];
  const float* ln2_g = (const float*)d_in[7];
  const float* ln2_b = (const float*)d_in[8];
  const float* fc1_w = (const float*)d_in[9];
  const float* fc1_b = (const float*)d_in[10];
  const float* ffg = (const float*)d_in[11];
  const float* ffb = (const float*)d_in[12];
  const float* fc2_w = (const float*)d_in[13];
  const float* fc2_b = (const float*)d_in[14];
  float* out = (float*)d_out;

  char* ws = (char*)d_ws;
  size_t off = 0;
  auto alloc = [&](size_t n) { char* p = ws + off; off += (n + 255) & ~(size_t)255; return p; };

  bf16_t* qkvT  = (bf16_t*)alloc(3072ull * 1024 * 2);
  bf16_t* projT = (bf16_t*)alloc(1024ull * 1024 * 2);
  bf16_t* fc1T  = (bf16_t*)alloc(4096ull * 1024 * 2);
  bf16_t* fc2T  = (bf16_t*)alloc(1024ull * 4096 * 2);
  float*  ropeC = (float*)alloc(2048ull * 32 * 4);
  float*  ropeS = (float*)alloc(2048ull * 32 * 4);
  bf16_t* hx    = (bf16_t*)alloc(4096ull * 1024 * 2);   // LN1 out; reused for LN2 out
  bf16_t* qbuf  = (bf16_t*)alloc(32ull * 2048 * 64 * 2);
  bf16_t* kbuf  = (bf16_t*)alloc(32ull * 2048 * 64 * 2);
  bf16_t* vtbuf = (bf16_t*)alloc(32ull * 64 * 2048 * 2);
  bf16_t* obuf  = (bf16_t*)alloc(4096ull * 1024 * 2);
  float*  x2    = (float*)alloc(4096ull * 1024 * 4);
  bf16_t* h1    = (bf16_t*)alloc(4096ull * 4096 * 2);
  bf16_t* hln   = (bf16_t*)qbuf;  // alias q..o region (dead after proj GEMM)

  // weights -> bf16 transposed
  transpose_w<<<dim3(96, 32), 256, 0, stream>>>(qkv_w, qkvT, 1024, 3072);
  transpose_w<<<dim3(32, 32), 256, 0, stream>>>(proj_w, projT, 1024, 1024);
  transpose_w<<<dim3(128, 32), 256, 0, stream>>>(fc1_w, fc1T, 1024, 4096);
  transpose_w<<<dim3(32, 128), 256, 0, stream>>>(fc2_w, fc2T, 4096, 1024);
  rope_tab<<<2048, 32, 0, stream>>>(ropeC, ropeS);

  // LN1
  ln_kernel<float, 1024><<<4096, 256, 0, stream>>>(x, ln1_g, ln1_b, hx);
  // QKV + RoPE + head scatter
  gemm_bt<EPI_QKV><<<dim3(24, 32), 256, 0, stream>>>(hx, qkvT, 4096, 3072, 1024, qkv_b,
      nullptr, nullptr, nullptr, qbuf, kbuf, vtbuf, ropeC, ropeS);
  // attention
  attn_kernel<<<dim3(16, 32), 256, 0, stream>>>(qbuf, kbuf, vtbuf, obuf);
  // proj + residual -> x2 (fp32)
  gemm_bt<EPI_RESID><<<dim3(8, 32), 256, 0, stream>>>(obuf, projT, 4096, 1024, 1024, proj_b,
      x, x2, nullptr, nullptr, nullptr, nullptr, nullptr, nullptr);
  // LN2 -> hx (bf16)
  ln_kernel<float, 1024><<<4096, 256, 0, stream>>>(x2, ln2_g, ln2_b, hx);
  // FC1 + GELU -> h1 (bf16)
  gemm_bt<EPI_GELU><<<dim3(32, 32), 256, 0, stream>>>(hx, fc1T, 4096, 4096, 1024, fc1_b,
      nullptr, nullptr, h1, nullptr, nullptr, nullptr, nullptr, nullptr);
  // ffn LN over hidden -> hln (bf16)
  ln_kernel<bf16_t, 4096><<<4096, 256, 0, stream>>>(h1, ffg, ffb, hln);
  // FC2 + residual -> out (fp32)
  gemm_bt<EPI_RESID><<<dim3(8, 32), 256, 0, stream>>>(hln, fc2T, 4096, 1024, 4096, fc2_b,
      x2, out, nullptr, nullptr, nullptr, nullptr, nullptr, nullptr);
}

// Round 4
// 416.457 us; speedup vs baseline: 1.0752x; 1.0752x over previous
//
#include <hip/hip_runtime.h>
#include <hip/hip_bf16.h>
#include <cmath>

typedef __bf16 bf16_t;
typedef __bf16 bf16x8 __attribute__((ext_vector_type(8)));
typedef float f32x4 __attribute__((ext_vector_type(4)));
typedef float f32x16 __attribute__((ext_vector_type(16)));
typedef unsigned short u16;
typedef unsigned int u32;

// fast exp: raw v_exp_f32 (exp2 domain) when available, else __expf (natural)
#if defined(__has_builtin)
#if __has_builtin(__builtin_amdgcn_exp2f)
#define ATTN_EXP(x) __builtin_amdgcn_exp2f(x)
#define ATTN_LOG2E 1.4426950408889634f
#endif
#endif
#ifndef ATTN_EXP
#define ATTN_EXP(x) __expf(x)
#define ATTN_LOG2E 1.0f
#endif

// ---------------- async global->LDS (16B per lane) ----------------
__device__ __forceinline__ void load16(const bf16_t* g, bf16_t* l) {
  __builtin_amdgcn_global_load_lds((const __attribute__((address_space(1))) u32*)g,
                                   (__attribute__((address_space(3))) u32*)l, 16, 0, 0);
}

__device__ __forceinline__ u32 pk2(float a, float b) {
  bf16_t x = (bf16_t)a, y = (bf16_t)b;
  u16 ux = __builtin_bit_cast(u16, x), uy = __builtin_bit_cast(u16, y);
  return (u32)ux | ((u32)uy << 16);
}

union V4U { u32 w[4]; bf16x8 v; };

// ---------------- fused prep: 4 weight transposes + rope table ----------------
__device__ __forceinline__ void tr32(const float* __restrict__ src, bf16_t* __restrict__ dst,
                                     int Kd, int Nd, int ntile, int ktile, int tid) {
  __shared__ float tile[32][33];
  int n0 = ntile * 32, k0 = ktile * 32;
  int tx = tid & 31, ty = tid >> 5;  // 32x8
  for (int i = ty; i < 32; i += 8)
    tile[i][tx] = src[(size_t)(k0 + i) * Nd + n0 + tx];
  __syncthreads();
  for (int i = ty; i < 32; i += 8)
    dst[(size_t)(n0 + i) * Kd + k0 + tx] = (bf16_t)tile[tx][i];
}

__global__ __launch_bounds__(256) void prep_kernel(
    const float* __restrict__ qkv_w, const float* __restrict__ proj_w,
    const float* __restrict__ fc1_w, const float* __restrict__ fc2_w,
    bf16_t* __restrict__ qkvT, bf16_t* __restrict__ projT,
    bf16_t* __restrict__ fc1T, bf16_t* __restrict__ fc2T,
    float* __restrict__ ropeC, float* __restrict__ ropeS) {
  int b = blockIdx.x, tid = threadIdx.x;
  if (b < 3072) {
    tr32(qkv_w, qkvT, 1024, 3072, b % 96, b / 96, tid);
  } else if (b < 4096) {
    int r = b - 3072; tr32(proj_w, projT, 1024, 1024, r % 32, r / 32, tid);
  } else if (b < 8192) {
    int r = b - 4096; tr32(fc1_w, fc1T, 1024, 4096, r % 128, r / 128, tid);
  } else if (b < 12288) {
    int r = b - 8192; tr32(fc2_w, fc2T, 4096, 1024, r % 32, r / 32, tid);
  } else {
    int idx = (b - 12288) * 256 + tid;     // 65536 = 2048 pos x 32 freq
    int pos = idx >> 5, t = idx & 31;
    float e = (float)(2 * t) / 64.0f;
    float inv = powf(10000.0f, -e);
    float a = (float)pos * inv;
    ropeC[idx] = cosf(a);
    ropeS[idx] = sinf(a);
  }
}

// ---------------- LayerNorm: one row per block, width W ----------------
template <typename TI, int W>
__global__ __launch_bounds__(256) void ln_kernel(const TI* __restrict__ in,
                                                 const float* __restrict__ g,
                                                 const float* __restrict__ b,
                                                 bf16_t* __restrict__ out) {
  constexpr int PT = W / 256;
  int row = blockIdx.x;
  const TI* p = in + (size_t)row * W;
  float vals[PT];
  float s = 0.f, q = 0.f;
  for (int i = 0; i < PT; ++i) {
    float v = (float)p[threadIdx.x + i * 256];
    vals[i] = v; s += v; q += v * v;
  }
  for (int off = 32; off; off >>= 1) { s += __shfl_xor(s, off); q += __shfl_xor(q, off); }
  __shared__ float red[8];
  int wave = threadIdx.x >> 6, lane = threadIdx.x & 63;
  if (lane == 0) { red[wave] = s; red[4 + wave] = q; }
  __syncthreads();
  s = red[0] + red[1] + red[2] + red[3];
  q = red[4] + red[5] + red[6] + red[7];
  float mu = s * (1.0f / W);
  float var = q * (1.0f / W) - mu * mu;
  float rstd = rsqrtf(var + 1e-5f);
  bf16_t* op = out + (size_t)row * W;
  for (int i = 0; i < PT; ++i) {
    int cix = threadIdx.x + i * 256;
    op[cix] = (bf16_t)((vals[i] - mu) * rstd * g[cix] + b[cix]);
  }
}

// ---------------- GEMM (m97 structure): C[m][n] = sum_k A[m][k]*Bt[n][k] ----------------
enum { EPI_QKV = 0, EPI_RESID = 1, EPI_GELU = 2 };

template <int EPI>
__global__ __launch_bounds__(256, 2) void gemm_bt(
    const bf16_t* __restrict__ A, const bf16_t* __restrict__ Bt, int M, int Nn, int K,
    const float* __restrict__ bias, const float* __restrict__ resid,
    float* __restrict__ outf, bf16_t* __restrict__ outb,
    bf16_t* __restrict__ qb, bf16_t* __restrict__ kb, bf16_t* __restrict__ vtb,
    const float* __restrict__ ropeC, const float* __restrict__ ropeS) {
  __shared__ bf16_t lsA[128 * 32];
  __shared__ bf16_t lsB[128 * 32];
  const int tid = threadIdx.x;
  const int lane = tid & 63;
  const int wave = tid >> 6;
  const int l16 = lane & 15, quad = lane >> 4;
  const int wm = (wave >> 1) * 64, wn = (wave & 1) * 64;
  const int m0 = blockIdx.y * 128, n0 = blockIdx.x * 128;

  f32x4 acc[4][4];
  for (int i = 0; i < 4; ++i)
    for (int j = 0; j < 4; ++j) acc[i][j] = {0.f, 0.f, 0.f, 0.f};

  for (int kk = 0; kk < K; kk += 32) {
    __syncthreads();
    for (int i = 0; i < 2; ++i) {
      int s = tid + i * 256;
      int row = s >> 2, ch = s & 3;
      load16(A + (size_t)(m0 + row) * K + kk + ch * 8, lsA + s * 8);
      load16(Bt + (size_t)(n0 + row) * K + kk + ch * 8, lsB + s * 8);
    }
    __syncthreads();
    bf16x8 af[4], bfr[4];
    for (int t = 0; t < 4; ++t) {
      af[t] = *(const bf16x8*)(lsA + (wm + t * 16 + l16) * 32 + quad * 8);
      bfr[t] = *(const bf16x8*)(lsB + (wn + t * 16 + l16) * 32 + quad * 8);
    }
    for (int mt = 0; mt < 4; ++mt)
      for (int nt = 0; nt < 4; ++nt)
        acc[mt][nt] = __builtin_amdgcn_mfma_f32_16x16x32_bf16(af[mt], bfr[nt], acc[mt][nt], 0, 0, 0);
  }

  // epilogue: row = m0+wm+mt*16+quad*4+r, col = n0+wn+nt*16+l16
  for (int mt = 0; mt < 4; ++mt) {
    for (int nt = 0; nt < 4; ++nt) {
      int gn = n0 + wn + nt * 16 + l16;
      int gm0 = m0 + wm + mt * 16 + quad * 4;
      if constexpr (EPI == EPI_QKV) {
        int which = gn >> 10;              // 0=q 1=k 2=v (uniform per nt)
        int hd = gn & 1023, head = hd >> 6, d = hd & 63;
        if (which == 2) {
          u32 lo, hi;
          {
            float v0 = acc[mt][nt][0] + bias[gn];
            float v1 = acc[mt][nt][1] + bias[gn];
            float v2 = acc[mt][nt][2] + bias[gn];
            float v3 = acc[mt][nt][3] + bias[gn];
            lo = pk2(v0, v1);
            hi = pk2(v2, v3);
          }
          int b = gm0 >> 11, pos = gm0 & 2047;
          int bh = b * 16 + head;
          uint2 pk; pk.x = lo; pk.y = hi;
          *(uint2*)(vtb + ((size_t)bh * 64 + d) * 2048 + pos) = pk;
        } else {
          bf16_t* dst = (which == 0) ? qb : kb;
          int t = d >> 1;
          for (int r = 0; r < 4; ++r) {
            float v = acc[mt][nt][r] + bias[gn];
            float pn = __shfl_xor(v, 1);  // partner column (d^1), same row
            int gm = gm0 + r;
            int b = gm >> 11, pos = gm & 2047;
            float cc = ropeC[pos * 32 + t], ss = ropeS[pos * 32 + t];
            float o = (d & 1) ? (v * cc + pn * ss) : (v * cc - pn * ss);
            dst[(((size_t)(b * 16 + head)) * 2048 + pos) * 64 + d] = (bf16_t)o;
          }
        }
      } else if constexpr (EPI == EPI_GELU) {
        for (int r = 0; r < 4; ++r) {
          int gm = gm0 + r;
          float v = acc[mt][nt][r] + bias[gn];
          float g = 0.5f * v * (1.0f + erff(v * 0.70710678118654752f));
          outb[(size_t)gm * Nn + gn] = (bf16_t)g;
        }
      } else {  // EPI_RESID: out = acc + bias + resid (fp32)
        for (int r = 0; r < 4; ++r) {
          int gm = gm0 + r;
          size_t idx = (size_t)gm * Nn + gn;
          outf[idx] = acc[mt][nt][r] + bias[gn] + resid[idx];
        }
      }
    }
  }
}

// ---------------- Flash attention, 32x32 MFMA, S^T/O^T orientation ----------------
// q,k: [BH][2048][64] bf16 (RoPE applied). vt: [BH][64][2048] bf16.
// o: [B][N][H*64] bf16. grid: (16 q-tiles, 32 bh), 256 threads, 32 q-rows/wave.
// Double-buffered K/V staging, one barrier per K-tile.
// 32x32x16 layouts: A[m=lane&31][k=(lane>>5)*8+j]; B[k=(lane>>5)*8+j][n=lane&31];
// C/D: col=lane&31, row=(reg&3)+8*(reg>>2)+4*(lane>>5).
__global__ __launch_bounds__(256, 2) void attn_kernel(
    const bf16_t* __restrict__ q, const bf16_t* __restrict__ k,
    const bf16_t* __restrict__ vt, bf16_t* __restrict__ o) {
  __shared__ bf16_t lsK[2][128 * 64];   // [key][d], 16B chunks swizzled: slot=c^(row&7)
  __shared__ bf16_t lsV[2][64 * 128];   // [d][key], slot=c^(row&7), 16 chunks/row

  const int tid = threadIdx.x, lane = tid & 63, wave = tid >> 6;
  const int c31 = lane & 31, hi = lane >> 5, h7 = c31 & 7;
  const int bh = blockIdx.y, qt = blockIdx.x;
  const int b = bh >> 4, h = bh & 15;
  const bf16_t* qp = q + (size_t)bh * 2048 * 64;
  const bf16_t* kp = k + (size_t)bh * 2048 * 64;
  const bf16_t* vp = vt + (size_t)bh * 64 * 2048;
  const int qrow0 = qt * 128 + wave * 32;
  const int qrow = qrow0 + c31;

  // Q B-frags: B[k=d][n=qrow]: lane needs q[qrow][ks*16+hi*8 .. +7], scaled by
  // 0.125 * (log2e if exp2 domain).
  const float QS = 0.125f * ATTN_LOG2E;
  bf16x8 qb[4];
#pragma unroll
  for (int ks = 0; ks < 4; ++ks) {
    bf16x8 t = *(const bf16x8*)(qp + (size_t)qrow * 64 + ks * 16 + hi * 8);
#pragma unroll
    for (int j = 0; j < 8; ++j) t[j] = (bf16_t)((float)t[j] * QS);
    qb[ks] = t;
  }

  f32x16 oacc[2];
  oacc[0] = 0.f; oacc[1] = 0.f;
  float mstate = -3.0e38f, lstate = 0.f;

  // staging: per thread 4 K-chunks + 4 V-chunks of 16B
  auto stage = [&](int kt, int buf) {
    const bf16_t* kg = kp + (size_t)kt * 128 * 64;
    bf16_t* lk = &lsK[buf][0];
    bf16_t* lv = &lsV[buf][0];
#pragma unroll
    for (int i = 0; i < 4; ++i) {
      int s = tid + i * 256;
      int kr = s >> 3, kc = (s & 7) ^ (kr & 7);
      load16(kg + (size_t)kr * 64 + kc * 8, lk + s * 8);
      int vr = s >> 4, vc = (s & 15) ^ (vr & 7);
      load16(vp + (size_t)vr * 2048 + kt * 128 + vc * 8, lv + s * 8);
    }
  };

  stage(0, 0);
  for (int kt = 0; kt < 16; ++kt) {
    __syncthreads();                    // drains async loads -> buf[kt&1] ready
    if (kt < 15) stage(kt + 1, (kt + 1) & 1);
    const bf16_t* lk = &lsK[kt & 1][0];
    const bf16_t* lv = &lsV[kt & 1][0];

    // S^T = K * Q^T : sacc[nt] covers keys nt*32..+31 x qrows (col=c31)
    f32x16 sacc[4];
    sacc[0] = 0.f; sacc[1] = 0.f; sacc[2] = 0.f; sacc[3] = 0.f;
#pragma unroll
    for (int ks = 0; ks < 4; ++ks) {
      int cs = ((ks * 2 + hi) ^ h7) * 8;
#pragma unroll
      for (int nt = 0; nt < 4; ++nt) {
        bf16x8 kf = *(const bf16x8*)(lk + (nt * 32 + c31) * 64 + cs);
        sacc[nt] = __builtin_amdgcn_mfma_f32_32x32x16_bf16(kf, qb[ks], sacc[nt], 0, 0, 0);
      }
    }

    // online softmax (exp2 domain); all state per-lane for qrow=c31
    float mx = sacc[0][0];
#pragma unroll
    for (int nt = 0; nt < 4; ++nt)
#pragma unroll
      for (int r = 0; r < 16; ++r) mx = fmaxf(mx, sacc[nt][r]);
    mx = fmaxf(mx, __shfl_xor(mx, 32));
    float mnew = fmaxf(mstate, mx);
    float alpha = ATTN_EXP(mstate - mnew);
    mstate = mnew;
    float rs = 0.f;
    u32 u[4][4][2];
#pragma unroll
    for (int nt = 0; nt < 4; ++nt)
#pragma unroll
      for (int t = 0; t < 4; ++t) {
        float p0 = ATTN_EXP(sacc[nt][4 * t + 0] - mnew);
        float p1 = ATTN_EXP(sacc[nt][4 * t + 1] - mnew);
        float p2 = ATTN_EXP(sacc[nt][4 * t + 2] - mnew);
        float p3 = ATTN_EXP(sacc[nt][4 * t + 3] - mnew);
        rs += (p0 + p1) + (p2 + p3);
        u[nt][t][0] = pk2(p0, p1);
        u[nt][t][1] = pk2(p2, p3);
      }
    rs += __shfl_xor(rs, 32);
    lstate = lstate * alpha + rs;
#pragma unroll
    for (int dt = 0; dt < 2; ++dt)
#pragma unroll
      for (int r = 0; r < 16; ++r) oacc[dt][r] *= alpha;

    // O^T += V^T * P^T. B-frag(P^T) for ks: keys ks*16+hi*8..+7 at qrow=c31.
#pragma unroll
    for (int ks = 0; ks < 8; ++ks) {
      int n = ks >> 1, t0 = (ks & 1) * 2;
      u32 a0 = u[n][t0][0], a1 = u[n][t0][1];
      u32 b0 = u[n][t0 + 1][0], b1 = u[n][t0 + 1][1];
      u32 ax0 = (u32)__shfl_xor((int)a0, 32), ax1 = (u32)__shfl_xor((int)a1, 32);
      u32 bx0 = (u32)__shfl_xor((int)b0, 32), bx1 = (u32)__shfl_xor((int)b1, 32);
      V4U f;
      f.w[0] = hi ? bx0 : a0;
      f.w[1] = hi ? bx1 : a1;
      f.w[2] = hi ? b0 : ax0;
      f.w[3] = hi ? b1 : ax1;
      bf16x8 pf = f.v;
      int cs = ((ks * 2 + hi) ^ h7) * 8;
#pragma unroll
      for (int dt = 0; dt < 2; ++dt) {
        bf16x8 vf = *(const bf16x8*)(lv + (dt * 32 + c31) * 128 + cs);
        oacc[dt] = __builtin_amdgcn_mfma_f32_32x32x16_bf16(vf, pf, oacc[dt], 0, 0, 0);
      }
    }
  }

  // epilogue: O^T[d][qrow], lane col=qrow=c31, row d=(reg&3)+8*(reg>>2)+4*hi+32*dt
  float inv = 1.0f / lstate;
  bf16_t* orow = o + ((size_t)(b * 2048 + qrow)) * 1024 + h * 64;
#pragma unroll
  for (int dt = 0; dt < 2; ++dt)
#pragma unroll
    for (int t = 0; t < 4; ++t) {
      int d0 = dt * 32 + 8 * t + 4 * hi;
      uint2 pk;
      pk.x = pk2(oacc[dt][4 * t + 0] * inv, oacc[dt][4 * t + 1] * inv);
      pk.y = pk2(oacc[dt][4 * t + 2] * inv, oacc[dt][4 * t + 3] * inv);
      *(uint2*)(orow + d0) = pk;
    }
}

// ---------------- launch ----------------
extern "C" void kernel_launch(void* const* d_in, const int* in_sizes, int n_in,
                              void* d_out, int out_size, void* d_ws, size_t ws_size,
                              hipStream_t stream) {
  const float* x = (const float*)d_in[0];
  const float* ln1_g = (const float*)d_in[1];
  const float* ln1_b = (const float*)d_in[2];
  const float* qkv_w = (const float*)d_in[3];
  const float* qkv_b = (const float*)d_in[4];
  const float* proj_w = (const float*)d_in[5];
  const float* proj_b = (const float*)d_in[6];
  const float* ln2_g = (const float*)d_in[7];
  const float* ln2_b = (const float*)d_in[8];
  const float* fc1_w = (const float*)d_in[9];
  const float* fc1_b = (const float*)d_in[10];
  const float* ffg = (const float*)d_in[11];
  const float* ffb = (const float*)d_in[12];
  const float* fc2_w = (const float*)d_in[13];
  const float* fc2_b = (const float*)d_in[14];
  float* out = (float*)d_out;

  char* ws = (char*)d_ws;
  size_t off = 0;
  auto alloc = [&](size_t n) { char* p = ws + off; off += (n + 255) & ~(size_t)255; return p; };

  bf16_t* qkvT  = (bf16_t*)alloc(3072ull * 1024 * 2);
  bf16_t* projT = (bf16_t*)alloc(1024ull * 1024 * 2);
  bf16_t* fc1T  = (bf16_t*)alloc(4096ull * 1024 * 2);
  bf16_t* fc2T  = (bf16_t*)alloc(1024ull * 4096 * 2);
  float*  ropeC = (float*)alloc(2048ull * 32 * 4);
  float*  ropeS = (float*)alloc(2048ull * 32 * 4);
  bf16_t* hx    = (bf16_t*)alloc(4096ull * 1024 * 2);   // LN1 out; reused for LN2 out
  bf16_t* qbuf  = (bf16_t*)alloc(32ull * 2048 * 64 * 2);
  bf16_t* kbuf  = (bf16_t*)alloc(32ull * 2048 * 64 * 2);
  bf16_t* vtbuf = (bf16_t*)alloc(32ull * 64 * 2048 * 2);
  bf16_t* obuf  = (bf16_t*)alloc(4096ull * 1024 * 2);
  float*  x2    = (float*)alloc(4096ull * 1024 * 4);
  bf16_t* h1    = (bf16_t*)alloc(4096ull * 4096 * 2);
  bf16_t* hln   = (bf16_t*)qbuf;  // alias q..o region (dead after proj GEMM)

  // fused: weights -> bf16 transposed + rope table
  prep_kernel<<<12544, 256, 0, stream>>>(qkv_w, proj_w, fc1_w, fc2_w,
                                         qkvT, projT, fc1T, fc2T, ropeC, ropeS);

  // LN1
  ln_kernel<float, 1024><<<4096, 256, 0, stream>>>(x, ln1_g, ln1_b, hx);
  // QKV + RoPE + head scatter
  gemm_bt<EPI_QKV><<<dim3(24, 32), 256, 0, stream>>>(hx, qkvT, 4096, 3072, 1024, qkv_b,
      nullptr, nullptr, nullptr, qbuf, kbuf, vtbuf, ropeC, ropeS);
  // attention
  attn_kernel<<<dim3(16, 32), 256, 0, stream>>>(qbuf, kbuf, vtbuf, obuf);
  // proj + residual -> x2 (fp32)
  gemm_bt<EPI_RESID><<<dim3(8, 32), 256, 0, stream>>>(obuf, projT, 4096, 1024, 1024, proj_b,
      x, x2, nullptr, nullptr, nullptr, nullptr, nullptr, nullptr);
  // LN2 -> hx (bf16)
  ln_kernel<float, 1024><<<4096, 256, 0, stream>>>(x2, ln2_g, ln2_b, hx);
  // FC1 + GELU -> h1 (bf16)
  gemm_bt<EPI_GELU><<<dim3(32, 32), 256, 0, stream>>>(hx, fc1T, 4096, 4096, 1024, fc1_b,
      nullptr, nullptr, h1, nullptr, nullptr, nullptr, nullptr, nullptr);
  // ffn LN over hidden -> hln (bf16)
  ln_kernel<bf16_t, 4096><<<4096, 256, 0, stream>>>(h1, ffg, ffb, hln);
  // FC2 + residual -> out (fp32)
  gemm_bt<EPI_RESID><<<dim3(8, 32), 256, 0, stream>>>(hln, fc2T, 4096, 1024, 4096, fc2_b,
      x2, out, nullptr, nullptr, nullptr, nullptr, nullptr, nullptr);
}

// Round 5
// 398.530 us; speedup vs baseline: 1.1236x; 1.0450x over previous
//
#include <hip/hip_runtime.h>
#include <hip/hip_bf16.h>
#include <cmath>

typedef __bf16 bf16_t;
typedef __bf16 bf16x8 __attribute__((ext_vector_type(8)));
typedef float f32x4 __attribute__((ext_vector_type(4)));
typedef float f32x16 __attribute__((ext_vector_type(16)));
typedef unsigned short u16;
typedef unsigned int u32;

// fast exp: raw v_exp_f32 (exp2 domain) when available, else __expf (natural)
#if defined(__has_builtin)
#if __has_builtin(__builtin_amdgcn_exp2f)
#define ATTN_EXP(x) __builtin_amdgcn_exp2f(x)
#define ATTN_LOG2E 1.4426950408889634f
#endif
#endif
#ifndef ATTN_EXP
#define ATTN_EXP(x) __expf(x)
#define ATTN_LOG2E 1.0f
#endif

// ---------------- async global->LDS (16B per lane) ----------------
__device__ __forceinline__ void load16(const bf16_t* g, bf16_t* l) {
  __builtin_amdgcn_global_load_lds((const __attribute__((address_space(1))) u32*)g,
                                   (__attribute__((address_space(3))) u32*)l, 16, 0, 0);
}

__device__ __forceinline__ u32 pk2(float a, float b) {
  bf16_t x = (bf16_t)a, y = (bf16_t)b;
  u16 ux = __builtin_bit_cast(u16, x), uy = __builtin_bit_cast(u16, y);
  return (u32)ux | ((u32)uy << 16);
}

union V4U { u32 w[4]; bf16x8 v; };

// ---------------- fused prep: 4 weight transposes + rope table ----------------
__device__ __forceinline__ void tr32(const float* __restrict__ src, bf16_t* __restrict__ dst,
                                     int Kd, int Nd, int ntile, int ktile, int tid) {
  __shared__ float tile[32][33];
  int n0 = ntile * 32, k0 = ktile * 32;
  int tx = tid & 31, ty = tid >> 5;  // 32x8
  for (int i = ty; i < 32; i += 8)
    tile[i][tx] = src[(size_t)(k0 + i) * Nd + n0 + tx];
  __syncthreads();
  for (int i = ty; i < 32; i += 8)
    dst[(size_t)(n0 + i) * Kd + k0 + tx] = (bf16_t)tile[tx][i];
}

__global__ __launch_bounds__(256) void prep_kernel(
    const float* __restrict__ qkv_w, const float* __restrict__ proj_w,
    const float* __restrict__ fc1_w, const float* __restrict__ fc2_w,
    bf16_t* __restrict__ qkvT, bf16_t* __restrict__ projT,
    bf16_t* __restrict__ fc1T, bf16_t* __restrict__ fc2T,
    float* __restrict__ ropeC, float* __restrict__ ropeS) {
  int b = blockIdx.x, tid = threadIdx.x;
  if (b < 3072) {
    tr32(qkv_w, qkvT, 1024, 3072, b % 96, b / 96, tid);
  } else if (b < 4096) {
    int r = b - 3072; tr32(proj_w, projT, 1024, 1024, r % 32, r / 32, tid);
  } else if (b < 8192) {
    int r = b - 4096; tr32(fc1_w, fc1T, 1024, 4096, r % 128, r / 128, tid);
  } else if (b < 12288) {
    int r = b - 8192; tr32(fc2_w, fc2T, 4096, 1024, r % 32, r / 32, tid);
  } else {
    int idx = (b - 12288) * 256 + tid;     // 65536 = 2048 pos x 32 freq
    int pos = idx >> 5, t = idx & 31;
    float e = (float)(2 * t) / 64.0f;
    float inv = powf(10000.0f, -e);
    float a = (float)pos * inv;
    ropeC[idx] = cosf(a);
    ropeS[idx] = sinf(a);
  }
}

// ---------------- LayerNorm: one row per block, width W ----------------
template <typename TI, int W>
__global__ __launch_bounds__(256) void ln_kernel(const TI* __restrict__ in,
                                                 const float* __restrict__ g,
                                                 const float* __restrict__ b,
                                                 bf16_t* __restrict__ out) {
  constexpr int PT = W / 256;
  int row = blockIdx.x;
  const TI* p = in + (size_t)row * W;
  float vals[PT];
  float s = 0.f, q = 0.f;
  for (int i = 0; i < PT; ++i) {
    float v = (float)p[threadIdx.x + i * 256];
    vals[i] = v; s += v; q += v * v;
  }
  for (int off = 32; off; off >>= 1) { s += __shfl_xor(s, off); q += __shfl_xor(q, off); }
  __shared__ float red[8];
  int wave = threadIdx.x >> 6, lane = threadIdx.x & 63;
  if (lane == 0) { red[wave] = s; red[4 + wave] = q; }
  __syncthreads();
  s = red[0] + red[1] + red[2] + red[3];
  q = red[4] + red[5] + red[6] + red[7];
  float mu = s * (1.0f / W);
  float var = q * (1.0f / W) - mu * mu;
  float rstd = rsqrtf(var + 1e-5f);
  bf16_t* op = out + (size_t)row * W;
  for (int i = 0; i < PT; ++i) {
    int cix = threadIdx.x + i * 256;
    op[cix] = (bf16_t)((vals[i] - mu) * rstd * g[cix] + b[cix]);
  }
}

// ---------------- GEMM: C[m][n] = sum_k A[m][k]*Bt[n][k] ----------------
// Double-buffered staging (1 barrier/K-iter), XOR-swizzled LDS chunks.
// TM = 128 (4x4 acc/wave) or 64 (2x4 acc/wave, 2x grid for skinny-N).
enum { EPI_QKV = 0, EPI_RESID = 1, EPI_GELU = 2 };

template <int EPI, int TM>
__global__ __launch_bounds__(256, 2) void gemm_bt(
    const bf16_t* __restrict__ A, const bf16_t* __restrict__ Bt, int M, int Nn, int K,
    const float* __restrict__ bias, const float* __restrict__ resid,
    float* __restrict__ outf, bf16_t* __restrict__ outb,
    bf16_t* __restrict__ qb, bf16_t* __restrict__ kb, bf16_t* __restrict__ vtb,
    const float* __restrict__ ropeC, const float* __restrict__ ropeS) {
  constexpr int MT = TM / 32;                 // mfma m-tiles per wave
  __shared__ bf16_t lsA[2][TM * 32];
  __shared__ bf16_t lsB[2][128 * 32];
  const int tid = threadIdx.x;
  const int lane = tid & 63;
  const int wave = tid >> 6;
  const int l16 = lane & 15, quad = lane >> 4;
  const int wm = (wave >> 1) * (TM / 2), wn = (wave & 1) * 64;
  const int m0 = blockIdx.y * TM, n0 = blockIdx.x * 128;

  f32x4 acc[MT][4];
  for (int i = 0; i < MT; ++i)
    for (int j = 0; j < 4; ++j) acc[i][j] = {0.f, 0.f, 0.f, 0.f};

  // staging with chunk swizzle: LDS slot s holds global chunk (s&3)^(row&3)
  auto stage = [&](int kk, int buf) {
    bf16_t* la = &lsA[buf][0];
    bf16_t* lb = &lsB[buf][0];
#pragma unroll
    for (int i = 0; i < TM / 64; ++i) {
      int s = tid + i * 256;
      int row = s >> 2, ch = (s & 3) ^ (row & 3);
      load16(A + (size_t)(m0 + row) * K + kk + ch * 8, la + s * 8);
    }
#pragma unroll
    for (int i = 0; i < 2; ++i) {
      int s = tid + i * 256;
      int row = s >> 2, ch = (s & 3) ^ (row & 3);
      load16(Bt + (size_t)(n0 + row) * K + kk + ch * 8, lb + s * 8);
    }
  };

  const int nk = K >> 5;
  stage(0, 0);
  for (int ki = 0; ki < nk; ++ki) {
    __syncthreads();                        // buf[ki&1] ready
    if (ki + 1 < nk) stage((ki + 1) << 5, (ki + 1) & 1);
    const bf16_t* la = &lsA[ki & 1][0];
    const bf16_t* lb = &lsB[ki & 1][0];
    bf16x8 af[MT], bfr[4];
#pragma unroll
    for (int t = 0; t < MT; ++t) {
      int row = wm + t * 16 + l16;
      af[t] = *(const bf16x8*)(la + row * 32 + (quad ^ (row & 3)) * 8);
    }
#pragma unroll
    for (int t = 0; t < 4; ++t) {
      int row = wn + t * 16 + l16;
      bfr[t] = *(const bf16x8*)(lb + row * 32 + (quad ^ (row & 3)) * 8);
    }
#pragma unroll
    for (int mt = 0; mt < MT; ++mt)
#pragma unroll
      for (int nt = 0; nt < 4; ++nt)
        acc[mt][nt] = __builtin_amdgcn_mfma_f32_16x16x32_bf16(af[mt], bfr[nt], acc[mt][nt], 0, 0, 0);
  }

  // epilogue: row = m0+wm+mt*16+quad*4+r, col = n0+wn+nt*16+l16
  for (int mt = 0; mt < MT; ++mt) {
    for (int nt = 0; nt < 4; ++nt) {
      int gn = n0 + wn + nt * 16 + l16;
      int gm0 = m0 + wm + mt * 16 + quad * 4;
      if constexpr (EPI == EPI_QKV) {
        int which = gn >> 10;              // 0=q 1=k 2=v (uniform per nt)
        int hd = gn & 1023, head = hd >> 6, d = hd & 63;
        if (which == 2) {
          u32 lo, hi;
          {
            float v0 = acc[mt][nt][0] + bias[gn];
            float v1 = acc[mt][nt][1] + bias[gn];
            float v2 = acc[mt][nt][2] + bias[gn];
            float v3 = acc[mt][nt][3] + bias[gn];
            lo = pk2(v0, v1);
            hi = pk2(v2, v3);
          }
          int b = gm0 >> 11, pos = gm0 & 2047;
          int bh = b * 16 + head;
          uint2 pk; pk.x = lo; pk.y = hi;
          *(uint2*)(vtb + ((size_t)bh * 64 + d) * 2048 + pos) = pk;
        } else {
          bf16_t* dst = (which == 0) ? qb : kb;
          int t = d >> 1;
          for (int r = 0; r < 4; ++r) {
            float v = acc[mt][nt][r] + bias[gn];
            float pn = __shfl_xor(v, 1);  // partner column (d^1), same row
            int gm = gm0 + r;
            int b = gm >> 11, pos = gm & 2047;
            float cc = ropeC[pos * 32 + t], ss = ropeS[pos * 32 + t];
            float o = (d & 1) ? (v * cc + pn * ss) : (v * cc - pn * ss);
            dst[(((size_t)(b * 16 + head)) * 2048 + pos) * 64 + d] = (bf16_t)o;
          }
        }
      } else if constexpr (EPI == EPI_GELU) {
        for (int r = 0; r < 4; ++r) {
          int gm = gm0 + r;
          float v = acc[mt][nt][r] + bias[gn];
          float g = 0.5f * v * (1.0f + erff(v * 0.70710678118654752f));
          outb[(size_t)gm * Nn + gn] = (bf16_t)g;
        }
      } else {  // EPI_RESID: out = acc + bias + resid (fp32)
        for (int r = 0; r < 4; ++r) {
          int gm = gm0 + r;
          size_t idx = (size_t)gm * Nn + gn;
          outf[idx] = acc[mt][nt][r] + bias[gn] + resid[idx];
        }
      }
    }
  }
}

// ---------------- Flash attention, 32x32 MFMA, S^T/O^T orientation ----------------
// q,k: [BH][2048][64] bf16 (RoPE applied). vt: [BH][64][2048] bf16.
// o: [B][N][H*64] bf16. grid: (16 q-tiles, 32 bh), 256 threads, 32 q-rows/wave.
// Double-buffered K/V staging, one barrier per K-tile.
// 32x32x16 layouts: A[m=lane&31][k=(lane>>5)*8+j]; B[k=(lane>>5)*8+j][n=lane&31];
// C/D: col=lane&31, row=(reg&3)+8*(reg>>2)+4*(lane>>5).
__global__ __launch_bounds__(256, 2) void attn_kernel(
    const bf16_t* __restrict__ q, const bf16_t* __restrict__ k,
    const bf16_t* __restrict__ vt, bf16_t* __restrict__ o) {
  __shared__ bf16_t lsK[2][128 * 64];   // [key][d], 16B chunks swizzled: slot=c^(row&7)
  __shared__ bf16_t lsV[2][64 * 128];   // [d][key], slot=c^(row&7), 16 chunks/row

  const int tid = threadIdx.x, lane = tid & 63, wave = tid >> 6;
  const int c31 = lane & 31, hi = lane >> 5, h7 = c31 & 7;
  const int bh = blockIdx.y, qt = blockIdx.x;
  const int b = bh >> 4, h = bh & 15;
  const bf16_t* qp = q + (size_t)bh * 2048 * 64;
  const bf16_t* kp = k + (size_t)bh * 2048 * 64;
  const bf16_t* vp = vt + (size_t)bh * 64 * 2048;
  const int qrow0 = qt * 128 + wave * 32;
  const int qrow = qrow0 + c31;

  // Q B-frags: B[k=d][n=qrow]: lane needs q[qrow][ks*16+hi*8 .. +7], scaled by
  // 0.125 * (log2e if exp2 domain).
  const float QS = 0.125f * ATTN_LOG2E;
  bf16x8 qb[4];
#pragma unroll
  for (int ks = 0; ks < 4; ++ks) {
    bf16x8 t = *(const bf16x8*)(qp + (size_t)qrow * 64 + ks * 16 + hi * 8);
#pragma unroll
    for (int j = 0; j < 8; ++j) t[j] = (bf16_t)((float)t[j] * QS);
    qb[ks] = t;
  }

  f32x16 oacc[2];
  oacc[0] = 0.f; oacc[1] = 0.f;
  float mstate = -3.0e38f, lstate = 0.f;

  // staging: per thread 4 K-chunks + 4 V-chunks of 16B
  auto stage = [&](int kt, int buf) {
    const bf16_t* kg = kp + (size_t)kt * 128 * 64;
    bf16_t* lk = &lsK[buf][0];
    bf16_t* lv = &lsV[buf][0];
#pragma unroll
    for (int i = 0; i < 4; ++i) {
      int s = tid + i * 256;
      int kr = s >> 3, kc = (s & 7) ^ (kr & 7);
      load16(kg + (size_t)kr * 64 + kc * 8, lk + s * 8);
      int vr = s >> 4, vc = (s & 15) ^ (vr & 7);
      load16(vp + (size_t)vr * 2048 + kt * 128 + vc * 8, lv + s * 8);
    }
  };

  stage(0, 0);
  for (int kt = 0; kt < 16; ++kt) {
    __syncthreads();                    // drains async loads -> buf[kt&1] ready
    if (kt < 15) stage(kt + 1, (kt + 1) & 1);
    const bf16_t* lk = &lsK[kt & 1][0];
    const bf16_t* lv = &lsV[kt & 1][0];

    // S^T = K * Q^T : sacc[nt] covers keys nt*32..+31 x qrows (col=c31)
    f32x16 sacc[4];
    sacc[0] = 0.f; sacc[1] = 0.f; sacc[2] = 0.f; sacc[3] = 0.f;
#pragma unroll
    for (int ks = 0; ks < 4; ++ks) {
      int cs = ((ks * 2 + hi) ^ h7) * 8;
#pragma unroll
      for (int nt = 0; nt < 4; ++nt) {
        bf16x8 kf = *(const bf16x8*)(lk + (nt * 32 + c31) * 64 + cs);
        sacc[nt] = __builtin_amdgcn_mfma_f32_32x32x16_bf16(kf, qb[ks], sacc[nt], 0, 0, 0);
      }
    }

    // online softmax (exp2 domain); all state per-lane for qrow=c31
    float mx = sacc[0][0];
#pragma unroll
    for (int nt = 0; nt < 4; ++nt)
#pragma unroll
      for (int r = 0; r < 16; ++r) mx = fmaxf(mx, sacc[nt][r]);
    mx = fmaxf(mx, __shfl_xor(mx, 32));
    float mnew = fmaxf(mstate, mx);
    float alpha = ATTN_EXP(mstate - mnew);
    mstate = mnew;
    float rs = 0.f;
    u32 u[4][4][2];
#pragma unroll
    for (int nt = 0; nt < 4; ++nt)
#pragma unroll
      for (int t = 0; t < 4; ++t) {
        float p0 = ATTN_EXP(sacc[nt][4 * t + 0] - mnew);
        float p1 = ATTN_EXP(sacc[nt][4 * t + 1] - mnew);
        float p2 = ATTN_EXP(sacc[nt][4 * t + 2] - mnew);
        float p3 = ATTN_EXP(sacc[nt][4 * t + 3] - mnew);
        rs += (p0 + p1) + (p2 + p3);
        u[nt][t][0] = pk2(p0, p1);
        u[nt][t][1] = pk2(p2, p3);
      }
    rs += __shfl_xor(rs, 32);
    lstate = lstate * alpha + rs;
#pragma unroll
    for (int dt = 0; dt < 2; ++dt)
#pragma unroll
      for (int r = 0; r < 16; ++r) oacc[dt][r] *= alpha;

    // O^T += V^T * P^T. B-frag(P^T) for ks: keys ks*16+hi*8..+7 at qrow=c31.
#pragma unroll
    for (int ks = 0; ks < 8; ++ks) {
      int n = ks >> 1, t0 = (ks & 1) * 2;
      u32 a0 = u[n][t0][0], a1 = u[n][t0][1];
      u32 b0 = u[n][t0 + 1][0], b1 = u[n][t0 + 1][1];
      u32 ax0 = (u32)__shfl_xor((int)a0, 32), ax1 = (u32)__shfl_xor((int)a1, 32);
      u32 bx0 = (u32)__shfl_xor((int)b0, 32), bx1 = (u32)__shfl_xor((int)b1, 32);
      V4U f;
      f.w[0] = hi ? bx0 : a0;
      f.w[1] = hi ? bx1 : a1;
      f.w[2] = hi ? b0 : ax0;
      f.w[3] = hi ? b1 : ax1;
      bf16x8 pf = f.v;
      int cs = ((ks * 2 + hi) ^ h7) * 8;
#pragma unroll
      for (int dt = 0; dt < 2; ++dt) {
        bf16x8 vf = *(const bf16x8*)(lv + (dt * 32 + c31) * 128 + cs);
        oacc[dt] = __builtin_amdgcn_mfma_f32_32x32x16_bf16(vf, pf, oacc[dt], 0, 0, 0);
      }
    }
  }

  // epilogue: O^T[d][qrow], lane col=qrow=c31, row d=(reg&3)+8*(reg>>2)+4*hi+32*dt
  float inv = 1.0f / lstate;
  bf16_t* orow = o + ((size_t)(b * 2048 + qrow)) * 1024 + h * 64;
#pragma unroll
  for (int dt = 0; dt < 2; ++dt)
#pragma unroll
    for (int t = 0; t < 4; ++t) {
      int d0 = dt * 32 + 8 * t + 4 * hi;
      uint2 pk;
      pk.x = pk2(oacc[dt][4 * t + 0] * inv, oacc[dt][4 * t + 1] * inv);
      pk.y = pk2(oacc[dt][4 * t + 2] * inv, oacc[dt][4 * t + 3] * inv);
      *(uint2*)(orow + d0) = pk;
    }
}

// ---------------- launch ----------------
extern "C" void kernel_launch(void* const* d_in, const int* in_sizes, int n_in,
                              void* d_out, int out_size, void* d_ws, size_t ws_size,
                              hipStream_t stream) {
  const float* x = (const float*)d_in[0];
  const float* ln1_g = (const float*)d_in[1];
  const float* ln1_b = (const float*)d_in[2];
  const float* qkv_w = (const float*)d_in[3];
  const float* qkv_b = (const float*)d_in[4];
  const float* proj_w = (const float*)d_in[5];
  const float* proj_b = (const float*)d_in[6];
  const float* ln2_g = (const float*)d_in[7];
  const float* ln2_b = (const float*)d_in[8];
  const float* fc1_w = (const float*)d_in[9];
  const float* fc1_b = (const float*)d_in[10];
  const float* ffg = (const float*)d_in[11];
  const float* ffb = (const float*)d_in[12];
  const float* fc2_w = (const float*)d_in[13];
  const float* fc2_b = (const float*)d_in[14];
  float* out = (float*)d_out;

  char* ws = (char*)d_ws;
  size_t off = 0;
  auto alloc = [&](size_t n) { char* p = ws + off; off += (n + 255) & ~(size_t)255; return p; };

  bf16_t* qkvT  = (bf16_t*)alloc(3072ull * 1024 * 2);
  bf16_t* projT = (bf16_t*)alloc(1024ull * 1024 * 2);
  bf16_t* fc1T  = (bf16_t*)alloc(4096ull * 1024 * 2);
  bf16_t* fc2T  = (bf16_t*)alloc(1024ull * 4096 * 2);
  float*  ropeC = (float*)alloc(2048ull * 32 * 4);
  float*  ropeS = (float*)alloc(2048ull * 32 * 4);
  bf16_t* hx    = (bf16_t*)alloc(4096ull * 1024 * 2);   // LN1 out; reused for LN2 out
  bf16_t* qbuf  = (bf16_t*)alloc(32ull * 2048 * 64 * 2);
  bf16_t* kbuf  = (bf16_t*)alloc(32ull * 2048 * 64 * 2);
  bf16_t* vtbuf = (bf16_t*)alloc(32ull * 64 * 2048 * 2);
  bf16_t* obuf  = (bf16_t*)alloc(4096ull * 1024 * 2);
  float*  x2    = (float*)alloc(4096ull * 1024 * 4);
  bf16_t* h1    = (bf16_t*)alloc(4096ull * 4096 * 2);
  bf16_t* hln   = (bf16_t*)qbuf;  // alias q..o region (dead after proj GEMM)

  // fused: weights -> bf16 transposed + rope table
  prep_kernel<<<12544, 256, 0, stream>>>(qkv_w, proj_w, fc1_w, fc2_w,
                                         qkvT, projT, fc1T, fc2T, ropeC, ropeS);

  // LN1
  ln_kernel<float, 1024><<<4096, 256, 0, stream>>>(x, ln1_g, ln1_b, hx);
  // QKV + RoPE + head scatter
  gemm_bt<EPI_QKV, 128><<<dim3(24, 32), 256, 0, stream>>>(hx, qkvT, 4096, 3072, 1024, qkv_b,
      nullptr, nullptr, nullptr, qbuf, kbuf, vtbuf, ropeC, ropeS);
  // attention
  attn_kernel<<<dim3(16, 32), 256, 0, stream>>>(qbuf, kbuf, vtbuf, obuf);
  // proj + residual -> x2 (fp32); TM=64 -> 512 blocks (2/CU)
  gemm_bt<EPI_RESID, 64><<<dim3(8, 64), 256, 0, stream>>>(obuf, projT, 4096, 1024, 1024, proj_b,
      x, x2, nullptr, nullptr, nullptr, nullptr, nullptr, nullptr);
  // LN2 -> hx (bf16)
  ln_kernel<float, 1024><<<4096, 256, 0, stream>>>(x2, ln2_g, ln2_b, hx);
  // FC1 + GELU -> h1 (bf16)
  gemm_bt<EPI_GELU, 128><<<dim3(32, 32), 256, 0, stream>>>(hx, fc1T, 4096, 4096, 1024, fc1_b,
      nullptr, nullptr, h1, nullptr, nullptr, nullptr, nullptr, nullptr);
  // ffn LN over hidden -> hln (bf16)
  ln_kernel<bf16_t, 4096><<<4096, 256, 0, stream>>>(h1, ffg, ffb, hln);
  // FC2 + residual -> out (fp32); TM=64 -> 512 blocks (2/CU)
  gemm_bt<EPI_RESID, 64><<<dim3(8, 64), 256, 0, stream>>>(hln, fc2T, 4096, 1024, 4096, fc2_b,
      x2, out, nullptr, nullptr, nullptr, nullptr, nullptr, nullptr);
}

// Round 6
// 392.810 us; speedup vs baseline: 1.1400x; 1.0146x over previous
//
#include <hip/hip_runtime.h>
#include <hip/hip_bf16.h>
#include <cmath>

typedef __bf16 bf16_t;
typedef __bf16 bf16x8 __attribute__((ext_vector_type(8)));
typedef float f32x4 __attribute__((ext_vector_type(4)));
typedef float f32x16 __attribute__((ext_vector_type(16)));
typedef unsigned short u16;
typedef unsigned int u32;

// fast exp: raw v_exp_f32 (exp2 domain) when available, else __expf (natural)
#if defined(__has_builtin)
#if __has_builtin(__builtin_amdgcn_exp2f)
#define ATTN_EXP(x) __builtin_amdgcn_exp2f(x)
#define ATTN_LOG2E 1.4426950408889634f
#endif
#endif
#ifndef ATTN_EXP
#define ATTN_EXP(x) __expf(x)
#define ATTN_LOG2E 1.0f
#endif

// ---------------- async global->LDS (16B per lane) ----------------
__device__ __forceinline__ void load16(const bf16_t* g, bf16_t* l) {
  __builtin_amdgcn_global_load_lds((const __attribute__((address_space(1))) u32*)g,
                                   (__attribute__((address_space(3))) u32*)l, 16, 0, 0);
}

__device__ __forceinline__ u32 pk2(float a, float b) {
  bf16_t x = (bf16_t)a, y = (bf16_t)b;
  u16 ux = __builtin_bit_cast(u16, x), uy = __builtin_bit_cast(u16, y);
  return (u32)ux | ((u32)uy << 16);
}

union V4U { u32 w[4]; bf16x8 v; };

// ---------------- fused prep: weight transposes (64x64, float4) + rope ----------------
// src [Kd][Nd] fp32 -> dst [Nd][Kd] bf16, one 64x64 tile per block.
__device__ __forceinline__ void tr64(const float* __restrict__ src, bf16_t* __restrict__ dst,
                                     int Kd, int Nd, int ntile, int ktile, int tid) {
  __shared__ float tile[64][68];   // stride 68 floats: 16B-aligned rows, no pow2 bank stride
  int n0 = ntile * 64, k0 = ktile * 64;
  int r = tid >> 2, c4 = (tid & 3) * 4;
  const float* sp = src + (size_t)(k0 + r) * Nd + n0;
#pragma unroll
  for (int c = 0; c < 4; ++c)
    *(float4*)&tile[r][c * 16 + c4] = *(const float4*)(sp + c * 16 + c4);
  __syncthreads();
  int n = tid >> 2;
  bf16_t* dp = dst + (size_t)(n0 + n) * Kd + k0;
#pragma unroll
  for (int c = 0; c < 4; ++c) {
    int kk = c * 16 + c4;
    uint2 pk;
    pk.x = pk2(tile[kk + 0][n], tile[kk + 1][n]);
    pk.y = pk2(tile[kk + 2][n], tile[kk + 3][n]);
    *(uint2*)(dp + kk) = pk;
  }
}

__global__ __launch_bounds__(256) void prep_kernel(
    const float* __restrict__ qkv_w, const float* __restrict__ proj_w,
    const float* __restrict__ fc1_w, const float* __restrict__ fc2_w,
    bf16_t* __restrict__ qkvT, bf16_t* __restrict__ projT,
    bf16_t* __restrict__ fc1T, bf16_t* __restrict__ fc2T,
    float* __restrict__ ropeC, float* __restrict__ ropeS) {
  int b = blockIdx.x, tid = threadIdx.x;
  if (b < 768) {                    // qkv: 16 k-tiles x 48 n-tiles
    tr64(qkv_w, qkvT, 1024, 3072, b % 48, b / 48, tid);
  } else if (b < 1024) {            // proj: 16 x 16
    int r = b - 768; tr64(proj_w, projT, 1024, 1024, r % 16, r / 16, tid);
  } else if (b < 2048) {            // fc1: 16 x 64
    int r = b - 1024; tr64(fc1_w, fc1T, 1024, 4096, r % 64, r / 64, tid);
  } else if (b < 3072) {            // fc2: 64 x 16
    int r = b - 2048; tr64(fc2_w, fc2T, 4096, 1024, r % 16, r / 16, tid);
  } else {
    int idx = (b - 3072) * 256 + tid;  // 65536 = 2048 pos x 32 freq
    int pos = idx >> 5, t = idx & 31;
    float e = (float)(2 * t) / 64.0f;
    float inv = powf(10000.0f, -e);
    float a = (float)pos * inv;
    ropeC[idx] = cosf(a);
    ropeS[idx] = sinf(a);
  }
}

// ---------------- LayerNorm: one row per block, width W ----------------
template <typename TI, int W>
__global__ __launch_bounds__(256) void ln_kernel(const TI* __restrict__ in,
                                                 const float* __restrict__ g,
                                                 const float* __restrict__ b,
                                                 bf16_t* __restrict__ out) {
  constexpr int PT = W / 256;
  int row = blockIdx.x;
  const TI* p = in + (size_t)row * W;
  float vals[PT];
  float s = 0.f, q = 0.f;
  for (int i = 0; i < PT; ++i) {
    float v = (float)p[threadIdx.x + i * 256];
    vals[i] = v; s += v; q += v * v;
  }
  for (int off = 32; off; off >>= 1) { s += __shfl_xor(s, off); q += __shfl_xor(q, off); }
  __shared__ float red[8];
  int wave = threadIdx.x >> 6, lane = threadIdx.x & 63;
  if (lane == 0) { red[wave] = s; red[4 + wave] = q; }
  __syncthreads();
  s = red[0] + red[1] + red[2] + red[3];
  q = red[4] + red[5] + red[6] + red[7];
  float mu = s * (1.0f / W);
  float var = q * (1.0f / W) - mu * mu;
  float rstd = rsqrtf(var + 1e-5f);
  bf16_t* op = out + (size_t)row * W;
  for (int i = 0; i < PT; ++i) {
    int cix = threadIdx.x + i * 256;
    op[cix] = (bf16_t)((vals[i] - mu) * rstd * g[cix] + b[cix]);
  }
}

// ---------------- GEMM: C[m][n] = sum_k A[m][k]*Bt[n][k] ----------------
// Double-buffered staging, XOR-swizzled LDS chunks, 1D grid with XCD-aware
// mapping: b = m + gy*n (gy%8==0) -> all n-tiles of one m-tile share an XCD/L2,
// so the A-tile is fetched into one L2 once and re-read locally.
enum { EPI_QKV = 0, EPI_RESID = 1, EPI_GELU = 2 };

template <int EPI, int TM>
__global__ __launch_bounds__(256, 2) void gemm_bt(
    const bf16_t* __restrict__ A, const bf16_t* __restrict__ Bt, int M, int Nn, int K,
    int gy,
    const float* __restrict__ bias, const float* __restrict__ resid,
    float* __restrict__ outf, bf16_t* __restrict__ outb,
    bf16_t* __restrict__ qb, bf16_t* __restrict__ kb, bf16_t* __restrict__ vtb,
    const float* __restrict__ ropeC, const float* __restrict__ ropeS) {
  constexpr int MT = TM / 32;                 // mfma m-tiles per wave
  __shared__ bf16_t lsA[2][TM * 32];
  __shared__ bf16_t lsB[2][128 * 32];
  const int tid = threadIdx.x;
  const int lane = tid & 63;
  const int wave = tid >> 6;
  const int l16 = lane & 15, quad = lane >> 4;
  const int wm = (wave >> 1) * (TM / 2), wn = (wave & 1) * 64;
  const int bb = blockIdx.x;
  const int m0 = (bb % gy) * TM, n0 = (bb / gy) * 128;

  f32x4 acc[MT][4];
  for (int i = 0; i < MT; ++i)
    for (int j = 0; j < 4; ++j) acc[i][j] = {0.f, 0.f, 0.f, 0.f};

  // staging with chunk swizzle: LDS slot s holds global chunk (s&3)^(row&3)
  auto stage = [&](int kk, int buf) {
    bf16_t* la = &lsA[buf][0];
    bf16_t* lb = &lsB[buf][0];
#pragma unroll
    for (int i = 0; i < TM / 64; ++i) {
      int s = tid + i * 256;
      int row = s >> 2, ch = (s & 3) ^ (row & 3);
      load16(A + (size_t)(m0 + row) * K + kk + ch * 8, la + s * 8);
    }
#pragma unroll
    for (int i = 0; i < 2; ++i) {
      int s = tid + i * 256;
      int row = s >> 2, ch = (s & 3) ^ (row & 3);
      load16(Bt + (size_t)(n0 + row) * K + kk + ch * 8, lb + s * 8);
    }
  };

  const int nk = K >> 5;
  stage(0, 0);
  for (int ki = 0; ki < nk; ++ki) {
    __syncthreads();                        // buf[ki&1] ready
    if (ki + 1 < nk) stage((ki + 1) << 5, (ki + 1) & 1);
    const bf16_t* la = &lsA[ki & 1][0];
    const bf16_t* lb = &lsB[ki & 1][0];
    bf16x8 af[MT], bfr[4];
#pragma unroll
    for (int t = 0; t < MT; ++t) {
      int row = wm + t * 16 + l16;
      af[t] = *(const bf16x8*)(la + row * 32 + (quad ^ (row & 3)) * 8);
    }
#pragma unroll
    for (int t = 0; t < 4; ++t) {
      int row = wn + t * 16 + l16;
      bfr[t] = *(const bf16x8*)(lb + row * 32 + (quad ^ (row & 3)) * 8);
    }
#pragma unroll
    for (int mt = 0; mt < MT; ++mt)
#pragma unroll
      for (int nt = 0; nt < 4; ++nt)
        acc[mt][nt] = __builtin_amdgcn_mfma_f32_16x16x32_bf16(af[mt], bfr[nt], acc[mt][nt], 0, 0, 0);
  }

  // epilogue: row = m0+wm+mt*16+quad*4+r, col = n0+wn+nt*16+l16
  for (int mt = 0; mt < MT; ++mt) {
    for (int nt = 0; nt < 4; ++nt) {
      int gn = n0 + wn + nt * 16 + l16;
      int gm0 = m0 + wm + mt * 16 + quad * 4;
      if constexpr (EPI == EPI_QKV) {
        int which = gn >> 10;              // 0=q 1=k 2=v (uniform per nt)
        int hd = gn & 1023, head = hd >> 6, d = hd & 63;
        if (which == 2) {
          u32 lo, hi;
          {
            float v0 = acc[mt][nt][0] + bias[gn];
            float v1 = acc[mt][nt][1] + bias[gn];
            float v2 = acc[mt][nt][2] + bias[gn];
            float v3 = acc[mt][nt][3] + bias[gn];
            lo = pk2(v0, v1);
            hi = pk2(v2, v3);
          }
          int b = gm0 >> 11, pos = gm0 & 2047;
          int bh = b * 16 + head;
          uint2 pk; pk.x = lo; pk.y = hi;
          *(uint2*)(vtb + ((size_t)bh * 64 + d) * 2048 + pos) = pk;
        } else {
          bf16_t* dst = (which == 0) ? qb : kb;
          int t = d >> 1;
          for (int r = 0; r < 4; ++r) {
            float v = acc[mt][nt][r] + bias[gn];
            float pn = __shfl_xor(v, 1);  // partner column (d^1), same row
            int gm = gm0 + r;
            int b = gm >> 11, pos = gm & 2047;
            float cc = ropeC[pos * 32 + t], ss = ropeS[pos * 32 + t];
            float o = (d & 1) ? (v * cc + pn * ss) : (v * cc - pn * ss);
            dst[(((size_t)(b * 16 + head)) * 2048 + pos) * 64 + d] = (bf16_t)o;
          }
        }
      } else if constexpr (EPI == EPI_GELU) {
        for (int r = 0; r < 4; ++r) {
          int gm = gm0 + r;
          float v = acc[mt][nt][r] + bias[gn];
          float g = 0.5f * v * (1.0f + erff(v * 0.70710678118654752f));
          outb[(size_t)gm * Nn + gn] = (bf16_t)g;
        }
      } else {  // EPI_RESID: out = acc + bias + resid (fp32)
        for (int r = 0; r < 4; ++r) {
          int gm = gm0 + r;
          size_t idx = (size_t)gm * Nn + gn;
          outf[idx] = acc[mt][nt][r] + bias[gn] + resid[idx];
        }
      }
    }
  }
}

// ---------------- Flash attention, 32x32 MFMA, S^T/O^T orientation ----------------
// q,k: [BH][2048][64] bf16 (RoPE applied). vt: [BH][64][2048] bf16.
// o: [B][N][H*64] bf16. grid: (16 q-tiles, 32 bh), 256 threads, 32 q-rows/wave.
// Double-buffered K/V staging, one barrier per K-tile.
// 32x32x16 layouts: A[m=lane&31][k=(lane>>5)*8+j]; B[k=(lane>>5)*8+j][n=lane&31];
// C/D: col=lane&31, row=(reg&3)+8*(reg>>2)+4*(lane>>5).
__global__ __launch_bounds__(256, 2) void attn_kernel(
    const bf16_t* __restrict__ q, const bf16_t* __restrict__ k,
    const bf16_t* __restrict__ vt, bf16_t* __restrict__ o) {
  __shared__ bf16_t lsK[2][128 * 64];   // [key][d], 16B chunks swizzled: slot=c^(row&7)
  __shared__ bf16_t lsV[2][64 * 128];   // [d][key], slot=c^(row&7), 16 chunks/row

  const int tid = threadIdx.x, lane = tid & 63, wave = tid >> 6;
  const int c31 = lane & 31, hi = lane >> 5, h7 = c31 & 7;
  const int bh = blockIdx.y, qt = blockIdx.x;
  const int b = bh >> 4, h = bh & 15;
  const bf16_t* qp = q + (size_t)bh * 2048 * 64;
  const bf16_t* kp = k + (size_t)bh * 2048 * 64;
  const bf16_t* vp = vt + (size_t)bh * 64 * 2048;
  const int qrow0 = qt * 128 + wave * 32;
  const int qrow = qrow0 + c31;

  // Q B-frags: B[k=d][n=qrow]: lane needs q[qrow][ks*16+hi*8 .. +7], scaled by
  // 0.125 * (log2e if exp2 domain).
  const float QS = 0.125f * ATTN_LOG2E;
  bf16x8 qb[4];
#pragma unroll
  for (int ks = 0; ks < 4; ++ks) {
    bf16x8 t = *(const bf16x8*)(qp + (size_t)qrow * 64 + ks * 16 + hi * 8);
#pragma unroll
    for (int j = 0; j < 8; ++j) t[j] = (bf16_t)((float)t[j] * QS);
    qb[ks] = t;
  }

  f32x16 oacc[2];
  oacc[0] = 0.f; oacc[1] = 0.f;
  float mstate = -3.0e38f, lstate = 0.f;

  // staging: per thread 4 K-chunks + 4 V-chunks of 16B
  auto stage = [&](int kt, int buf) {
    const bf16_t* kg = kp + (size_t)kt * 128 * 64;
    bf16_t* lk = &lsK[buf][0];
    bf16_t* lv = &lsV[buf][0];
#pragma unroll
    for (int i = 0; i < 4; ++i) {
      int s = tid + i * 256;
      int kr = s >> 3, kc = (s & 7) ^ (kr & 7);
      load16(kg + (size_t)kr * 64 + kc * 8, lk + s * 8);
      int vr = s >> 4, vc = (s & 15) ^ (vr & 7);
      load16(vp + (size_t)vr * 2048 + kt * 128 + vc * 8, lv + s * 8);
    }
  };

  stage(0, 0);
  for (int kt = 0; kt < 16; ++kt) {
    __syncthreads();                    // drains async loads -> buf[kt&1] ready
    if (kt < 15) stage(kt + 1, (kt + 1) & 1);
    const bf16_t* lk = &lsK[kt & 1][0];
    const bf16_t* lv = &lsV[kt & 1][0];

    // S^T = K * Q^T : sacc[nt] covers keys nt*32..+31 x qrows (col=c31)
    f32x16 sacc[4];
    sacc[0] = 0.f; sacc[1] = 0.f; sacc[2] = 0.f; sacc[3] = 0.f;
#pragma unroll
    for (int ks = 0; ks < 4; ++ks) {
      int cs = ((ks * 2 + hi) ^ h7) * 8;
#pragma unroll
      for (int nt = 0; nt < 4; ++nt) {
        bf16x8 kf = *(const bf16x8*)(lk + (nt * 32 + c31) * 64 + cs);
        sacc[nt] = __builtin_amdgcn_mfma_f32_32x32x16_bf16(kf, qb[ks], sacc[nt], 0, 0, 0);
      }
    }

    // online softmax (exp2 domain); all state per-lane for qrow=c31
    float mx = sacc[0][0];
#pragma unroll
    for (int nt = 0; nt < 4; ++nt)
#pragma unroll
      for (int r = 0; r < 16; ++r) mx = fmaxf(mx, sacc[nt][r]);
    mx = fmaxf(mx, __shfl_xor(mx, 32));
    float mnew = fmaxf(mstate, mx);
    float alpha = ATTN_EXP(mstate - mnew);
    mstate = mnew;
    float rs = 0.f;
    u32 u[4][4][2];
#pragma unroll
    for (int nt = 0; nt < 4; ++nt)
#pragma unroll
      for (int t = 0; t < 4; ++t) {
        float p0 = ATTN_EXP(sacc[nt][4 * t + 0] - mnew);
        float p1 = ATTN_EXP(sacc[nt][4 * t + 1] - mnew);
        float p2 = ATTN_EXP(sacc[nt][4 * t + 2] - mnew);
        float p3 = ATTN_EXP(sacc[nt][4 * t + 3] - mnew);
        rs += (p0 + p1) + (p2 + p3);
        u[nt][t][0] = pk2(p0, p1);
        u[nt][t][1] = pk2(p2, p3);
      }
    rs += __shfl_xor(rs, 32);
    lstate = lstate * alpha + rs;
#pragma unroll
    for (int dt = 0; dt < 2; ++dt)
#pragma unroll
      for (int r = 0; r < 16; ++r) oacc[dt][r] *= alpha;

    // O^T += V^T * P^T. B-frag(P^T) for ks: keys ks*16+hi*8..+7 at qrow=c31.
#pragma unroll
    for (int ks = 0; ks < 8; ++ks) {
      int n = ks >> 1, t0 = (ks & 1) * 2;
      u32 a0 = u[n][t0][0], a1 = u[n][t0][1];
      u32 b0 = u[n][t0 + 1][0], b1 = u[n][t0 + 1][1];
      u32 ax0 = (u32)__shfl_xor((int)a0, 32), ax1 = (u32)__shfl_xor((int)a1, 32);
      u32 bx0 = (u32)__shfl_xor((int)b0, 32), bx1 = (u32)__shfl_xor((int)b1, 32);
      V4U f;
      f.w[0] = hi ? bx0 : a0;
      f.w[1] = hi ? bx1 : a1;
      f.w[2] = hi ? b0 : ax0;
      f.w[3] = hi ? b1 : ax1;
      bf16x8 pf = f.v;
      int cs = ((ks * 2 + hi) ^ h7) * 8;
#pragma unroll
      for (int dt = 0; dt < 2; ++dt) {
        bf16x8 vf = *(const bf16x8*)(lv + (dt * 32 + c31) * 128 + cs);
        oacc[dt] = __builtin_amdgcn_mfma_f32_32x32x16_bf16(vf, pf, oacc[dt], 0, 0, 0);
      }
    }
  }

  // epilogue: O^T[d][qrow], lane col=qrow=c31, row d=(reg&3)+8*(reg>>2)+4*hi+32*dt
  float inv = 1.0f / lstate;
  bf16_t* orow = o + ((size_t)(b * 2048 + qrow)) * 1024 + h * 64;
#pragma unroll
  for (int dt = 0; dt < 2; ++dt)
#pragma unroll
    for (int t = 0; t < 4; ++t) {
      int d0 = dt * 32 + 8 * t + 4 * hi;
      uint2 pk;
      pk.x = pk2(oacc[dt][4 * t + 0] * inv, oacc[dt][4 * t + 1] * inv);
      pk.y = pk2(oacc[dt][4 * t + 2] * inv, oacc[dt][4 * t + 3] * inv);
      *(uint2*)(orow + d0) = pk;
    }
}

// ---------------- launch ----------------
extern "C" void kernel_launch(void* const* d_in, const int* in_sizes, int n_in,
                              void* d_out, int out_size, void* d_ws, size_t ws_size,
                              hipStream_t stream) {
  const float* x = (const float*)d_in[0];
  const float* ln1_g = (const float*)d_in[1];
  const float* ln1_b = (const float*)d_in[2];
  const float* qkv_w = (const float*)d_in[3];
  const float* qkv_b = (const float*)d_in[4];
  const float* proj_w = (const float*)d_in[5];
  const float* proj_b = (const float*)d_in[6];
  const float* ln2_g = (const float*)d_in[7];
  const float* ln2_b = (const float*)d_in[8];
  const float* fc1_w = (const float*)d_in[9];
  const float* fc1_b = (const float*)d_in[10];
  const float* ffg = (const float*)d_in[11];
  const float* ffb = (const float*)d_in[12];
  const float* fc2_w = (const float*)d_in[13];
  const float* fc2_b = (const float*)d_in[14];
  float* out = (float*)d_out;

  char* ws = (char*)d_ws;
  size_t off = 0;
  auto alloc = [&](size_t n) { char* p = ws + off; off += (n + 255) & ~(size_t)255; return p; };

  bf16_t* qkvT  = (bf16_t*)alloc(3072ull * 1024 * 2);
  bf16_t* projT = (bf16_t*)alloc(1024ull * 1024 * 2);
  bf16_t* fc1T  = (bf16_t*)alloc(4096ull * 1024 * 2);
  bf16_t* fc2T  = (bf16_t*)alloc(1024ull * 4096 * 2);
  float*  ropeC = (float*)alloc(2048ull * 32 * 4);
  float*  ropeS = (float*)alloc(2048ull * 32 * 4);
  bf16_t* hx    = (bf16_t*)alloc(4096ull * 1024 * 2);   // LN1 out; reused for LN2 out
  bf16_t* qbuf  = (bf16_t*)alloc(32ull * 2048 * 64 * 2);
  bf16_t* kbuf  = (bf16_t*)alloc(32ull * 2048 * 64 * 2);
  bf16_t* vtbuf = (bf16_t*)alloc(32ull * 64 * 2048 * 2);
  bf16_t* obuf  = (bf16_t*)alloc(4096ull * 1024 * 2);
  float*  x2    = (float*)alloc(4096ull * 1024 * 4);
  bf16_t* h1    = (bf16_t*)alloc(4096ull * 4096 * 2);
  bf16_t* hln   = (bf16_t*)qbuf;  // alias q..o region (dead after proj GEMM)

  // fused: weights -> bf16 transposed (64x64 float4 tiles) + rope table
  prep_kernel<<<3328, 256, 0, stream>>>(qkv_w, proj_w, fc1_w, fc2_w,
                                        qkvT, projT, fc1T, fc2T, ropeC, ropeS);

  // LN1
  ln_kernel<float, 1024><<<4096, 256, 0, stream>>>(x, ln1_g, ln1_b, hx);
  // QKV + RoPE + head scatter; 1D grid, gy=32 m-tiles
  gemm_bt<EPI_QKV, 128><<<768, 256, 0, stream>>>(hx, qkvT, 4096, 3072, 1024, 32, qkv_b,
      nullptr, nullptr, nullptr, qbuf, kbuf, vtbuf, ropeC, ropeS);
  // attention
  attn_kernel<<<dim3(16, 32), 256, 0, stream>>>(qbuf, kbuf, vtbuf, obuf);
  // proj + residual -> x2 (fp32); TM=64, gy=64
  gemm_bt<EPI_RESID, 64><<<512, 256, 0, stream>>>(obuf, projT, 4096, 1024, 1024, 64, proj_b,
      x, x2, nullptr, nullptr, nullptr, nullptr, nullptr, nullptr);
  // LN2 -> hx (bf16)
  ln_kernel<float, 1024><<<4096, 256, 0, stream>>>(x2, ln2_g, ln2_b, hx);
  // FC1 + GELU -> h1 (bf16); gy=32
  gemm_bt<EPI_GELU, 128><<<1024, 256, 0, stream>>>(hx, fc1T, 4096, 4096, 1024, 32, fc1_b,
      nullptr, nullptr, h1, nullptr, nullptr, nullptr, nullptr, nullptr);
  // ffn LN over hidden -> hln (bf16)
  ln_kernel<bf16_t, 4096><<<4096, 256, 0, stream>>>(h1, ffg, ffb, hln);
  // FC2 + residual -> out (fp32); TM=64, gy=64
  gemm_bt<EPI_RESID, 64><<<512, 256, 0, stream>>>(hln, fc2T, 4096, 1024, 4096, 64, fc2_b,
      x2, out, nullptr, nullptr, nullptr, nullptr, nullptr, nullptr);
}